// Round 1
// baseline (395.708 us; speedup 1.0000x reference)
//
#include <hip/hip_runtime.h>
#include <hip/hip_bf16.h>

#define NHD 8
#define HD  32
#define C_  256
#define TD_ 512
#define S_  256
#define N_  32768   // D*H*W
#define B_  2

typedef short bf16x8 __attribute__((ext_vector_type(8)));
typedef short bf16x4 __attribute__((ext_vector_type(4)));
typedef float f32x4  __attribute__((ext_vector_type(4)));

#define MFMA16(a,b,c) __builtin_amdgcn_mfma_f32_16x16x32_bf16(a,b,c,0,0,0)

__device__ __forceinline__ short f2bf(float f){
    __hip_bfloat16 h = __float2bfloat16(f);
    return *reinterpret_cast<short*>(&h);
}

// ---------------------------------------------------------------------------
// prep_fvtf (verified R6): fv f32 [b][c][n] -> fragment-ordered bf16
//   fvtf[b][ntile][cc][lane][8] = fv[b][cc*32+(lane>>4)*8+j][ntile*16+(lane&15)]
// ---------------------------------------------------------------------------
__global__ __launch_bounds__(256) void prep_fvtf(
    const float* __restrict__ fv, short* __restrict__ fvtf)
{
    __shared__ short Ts[64 * 128];   // 16 KB
    const int t = threadIdx.x;
    const int n0 = blockIdx.x * 128, c0 = blockIdx.y * 64, b = blockIdx.z;

#pragma unroll
    for (int i = 0; i < 8; ++i) {
        int c_loc = (t >> 5) + 8 * i;            // 0..63
        int u = t & 31;                           // n-unit (4 floats)
        float4 v = *(const float4*)&fv[(size_t)(b * C_ + c0 + c_loc) * N_ + n0 + u * 4];
        int up = u ^ (c_loc & 31);
        bf16x4 s4 = { f2bf(v.x), f2bf(v.y), f2bf(v.z), f2bf(v.w) };
        *(bf16x4*)&Ts[c_loc * 128 + up * 4] = s4;
    }
    __syncthreads();
#pragma unroll
    for (int p = 0; p < 4; ++p) {
        int idx = p * 256 + t;                    // 0..1023
        int lane = idx & 63, ccl = (idx >> 6) & 1, ntl = idx >> 7;
        bf16x8 r;
#pragma unroll
        for (int k = 0; k < 8; ++k) {
            int c = ccl * 32 + (lane >> 4) * 8 + k;
            int n = ntl * 16 + (lane & 15);
            r[k] = Ts[c * 128 + ((n >> 2) ^ (c & 31)) * 4 + (n & 3)];
        }
        size_t chunk = ((size_t)b * 2048 + (n0 >> 4) + ntl) * 8 + (c0 >> 5) + ccl;
        *(bf16x8*)&fvtf[chunk * 512 + lane * 8] = r;
    }
}

// ---------------------------------------------------------------------------
// prep_wf (verified R6): q_w/o_w fp32 [c][co] -> fragment-ordered bf16
// ---------------------------------------------------------------------------
__global__ __launch_bounds__(256) void prep_wf(
    const float* __restrict__ qw, const float* __restrict__ ow,
    short* __restrict__ wqf, short* __restrict__ wof)
{
    int gid = blockIdx.x * 256 + threadIdx.x;   // 64 blocks -> 16384
    int m = gid >> 13;
    int rest = gid & 8191;
    const float* src = m ? ow : qw;
    short* dst = m ? wof : wqf;
    int lane = rest & 63;
    int l15 = lane & 15, qd = lane >> 4;
    int cbase, co;
    if (m == 0) { int nt = rest >> 9, cc = (rest >> 6) & 7; cbase = cc * 32 + qd * 8; co = nt * 16 + l15; }
    else        { int hm = rest >> 6; cbase = (hm >> 4) * 32 + qd * 8; co = (hm & 15) * 16 + l15; }
    bf16x8 r;
#pragma unroll
    for (int j = 0; j < 8; ++j) r[j] = f2bf(src[(size_t)(cbase + j) * 256 + co]);
    *(bf16x8*)&dst[(size_t)rest * 8] = r;
}

// ---------------------------------------------------------------------------
// text stage (math verified R6; 1 token/block, 512 blocks).
// Outputs fragment-ordered kf/vf, indexing identical to R6.
// ---------------------------------------------------------------------------
__global__ __launch_bounds__(256) void text_stage(
    const float* __restrict__ text,
    const float* __restrict__ k_w, const float* __restrict__ k_b,
    const float* __restrict__ v_w, const float* __restrict__ v_b,
    const float* __restrict__ m1_w, const float* __restrict__ m1_b,
    const float* __restrict__ m2_w, const float* __restrict__ m2_b,
    short* __restrict__ kf, short* __restrict__ vf)
{
    __shared__ float t_s[TD_];
    __shared__ float h_s[C_];
    __shared__ float k_s[C_];
    const int tid = threadIdx.x;
    const int token = blockIdx.x;      // 0..511

    float2 tt = *(const float2*)&text[(size_t)token * TD_ + tid * 2];
    t_s[tid * 2] = tt.x; t_s[tid * 2 + 1] = tt.y;
    __syncthreads();

    float kv = k_b[tid], vv = v_b[tid], hv = m1_b[tid];
#pragma unroll 4
    for (int j = 0; j < TD_; ++j) {
        float tj = t_s[j];
        kv += tj * k_w[j * C_ + tid];
        vv += tj * v_w[j * C_ + tid];
        hv += tj * m1_w[j * C_ + tid];
    }
    float hg = 0.5f * hv * (1.0f + erff(hv * 0.70710678118654752f));
    h_s[tid] = hg;
    k_s[tid] = kv;
    __syncthreads();

    float ph = m2_b[tid];
#pragma unroll 4
    for (int j = 0; j < C_; ++j)
        ph += h_s[j] * m2_w[j * C_ + tid];

    const int t = tid & (HD - 1);
    const int nh = tid >> 5;
    const int b = token >> 8, s = token & (S_ - 1);
    const int bh = b * NHD + nh;
    float partner = (t < 16) ? -k_s[tid + 16] : k_s[tid - 16];
    float kr = kv * cosf(ph) + partner * sinf(ph);
    kf[(((size_t)bh * 16 + (s >> 4)) * 64 + (t >> 3) * 16 + (s & 15)) * 8 + (t & 7)] = f2bf(kr);
    vf[((((size_t)bh * 8 + (s >> 5)) * 2 + (t >> 4)) * 64 + ((s >> 3) & 3) * 16 + (t & 15)) * 8 + (s & 7)] = f2bf(vv);
}

// 3D rope freq (verified R3/R4/R6)
__device__ __forceinline__ float freq3d(int t, int n){
    int d = n >> 10, h = (n >> 5) & 31, w = n & 31;
    float pos, ex;
    if (t < 10)      { pos = (float)d; ex = (float)(2 * (t % 5)) * 0.1f; }
    else if (t < 20) { pos = (float)h; ex = (float)(2 * ((t - 10) % 5)) * 0.1f; }
    else             { pos = (float)w; ex = (float)(2 * ((t - 20) % 6)) * (1.0f / 12.0f); }
    return pos * expf(-ex * 9.210340371976184f);
}

// ---------------------------------------------------------------------------
// async global->LDS staging (16B/lane, linear; CK-style addrspace casts).
// LDS dest is wave-uniform base + lane*16 (HW semantics); global src per-lane.
// ---------------------------------------------------------------------------
typedef __attribute__((address_space(3))) unsigned int lds_u32;
typedef const __attribute__((address_space(1))) unsigned int glb_u32;

__device__ __forceinline__ void async_cp16(const short* g, short* l){
    __builtin_amdgcn_global_load_lds(
        (glb_u32*)(unsigned long long)g,
        (lds_u32*)(unsigned int)(unsigned long long)l,
        16, 0, 0);
}

// stage one 16 KB fragment-ordered head tile (verbatim copy, 4 rounds x 256 thr x 16B)
__device__ __forceinline__ void stage_tile(const short* __restrict__ g, short* l, int tid){
    const int wvb = tid & 192;            // (tid>>6)<<6 : wave-uniform
#pragma unroll
    for (int r = 0; r < 4; ++r)
        async_cp16(g + (r * 256 + tid) * 8, l + (r * 256 + wvb) * 8);
}

// ---------------------------------------------------------------------------
// FUSED: qproj + RoPE + attention + oproj.
// New this round:
//  - all 8 per-head Q A-frags held in registers (head loop fully unrolled ->
//    static aqh[] indexing), freeing the 32KB Qs LDS
//  - that 32KB (KV[]) is per-head K/V staging shared by all 4 waves, filled
//    with global_load_lds (zero VGPR cost), staged one head ahead so the DMA
//    overlaps oproj; drained by the __syncthreads at head top
//  - launch_bounds (256,3): ~170 unified regs so the compiler can prefetch WO
// LDS = KV 32KB + Pb 8KB = 40KB. Prologue reuses KV as wave-private Q-transpose
// scratch (wave wv owns KV[wv*4096 .. +4096), in-order per-wave DS).
// ---------------------------------------------------------------------------
__global__ __launch_bounds__(256, 3) void fused_visual(
    const short* __restrict__ fvtf, const short* __restrict__ wqf,
    const float* __restrict__ q_b, const short* __restrict__ kf,
    const short* __restrict__ vf, const short* __restrict__ wof,
    const float* __restrict__ o_b, float* __restrict__ out)
{
    __shared__ __align__(16) short KV[16384];       // 32 KB: K [0..8191], V [8192..16383]
    __shared__ __align__(16) short Pb[4 * 16 * 64]; // 8 KB (P; Ot aliases)
    const int tid = threadIdx.x;
    const int lane = tid & 63;
    const int l15 = tid & 15, qd = (tid >> 4) & 3, wv = tid >> 6;
    const int n0 = blockIdx.x * 64;
    const int b = blockIdx.y;
    const f32x4 z4 = {0.f, 0.f, 0.f, 0.f};
    const float scale = 0.17677669529663687f;  // 32^-0.5, folded into Q

    short* Qsc = KV + wv * 4096;   // wave-private 8KB transpose scratch (prologue only)

    // ---------------- qproj ----------------
    {
        f32x4 acc[16];
#pragma unroll
        for (int i = 0; i < 16; ++i) acc[i] = z4;
        const short* abase = fvtf + ((size_t)b * 2048 + (n0 >> 4) + wv) * 8 * 512 + lane * 8;
#pragma unroll
        for (int cc = 0; cc < 8; ++cc) {
            bf16x8 af = *(const bf16x8*)(abase + cc * 512);
#pragma unroll
            for (int nt = 0; nt < 16; ++nt) {
                bf16x8 bq = *(const bf16x8*)&wqf[((nt * 8 + cc) * 64 + lane) * 8];
                acc[nt] = MFMA16(af, bq, acc[nt]);
            }
        }
        // RoPE -> wave-private scratch (swizzled, R5-verified scheme; local rows 0..15)
#pragma unroll
        for (int r = 0; r < 4; ++r) {
            int lr = qd * 4 + r;                  // local row; (wv*16+lr)&7 == lr&7
            int n = n0 + wv * 16 + lr;
            int key = lr & 7;
            float f1 = freq3d(l15, n), f2 = freq3d(l15 + 16, n);
            float c1 = cosf(f1), s1 = sinf(f1), c2 = cosf(f2), s2 = sinf(f2);
#pragma unroll
            for (int hh = 0; hh < 8; ++hh) {
                float x1 = acc[2 * hh][r]     + q_b[hh * 32 + l15];
                float x2 = acc[2 * hh + 1][r] + q_b[hh * 32 + 16 + l15];
                int cb1 = (hh * 4 + (l15 >> 3)) ^ key;
                int cb2 = (hh * 4 + 2 + (l15 >> 3)) ^ key;
                Qsc[lr * 256 + cb1 * 8 + (l15 & 7)] = f2bf((x1 * c1 - x2 * s1) * scale);
                Qsc[lr * 256 + cb2 * 8 + (l15 & 7)] = f2bf((x2 * c2 + x1 * s2) * scale);
            }
        }
    }

    // all 8 per-head Q A-frags into registers (per-wave in-order DS: no barrier
    // needed between own writes and own reads)
    bf16x8 aqh[8];
#pragma unroll
    for (int h = 0; h < 8; ++h)
        aqh[h] = *(const bf16x8*)&Qsc[l15 * 256 + ((h * 4 + qd) ^ (l15 & 7)) * 8];

    __syncthreads();   // all waves done with KV scratch (lgkmcnt(0) drains aqh reads)
    // prologue stage: head 0 K/V
    stage_tile(kf + (size_t)(b * NHD) * 8192, KV, tid);
    stage_tile(vf + (size_t)(b * NHD) * 8192, KV + 8192, tid);

    // ---------------- attention + accumulated oproj ----------------
    f32x4 acc_co[16];
#pragma unroll
    for (int i = 0; i < 16; ++i) acc_co[i] = z4;
    short* Pw = Pb + wv * 16 * 64;
    short* Ow = Pw;   // alias (per-wave in-order DS makes this safe)

#pragma unroll
    for (int h = 0; h < 8; ++h) {
        // staging of head h drained here (compiler emits vmcnt(0) before barrier)
        __syncthreads();

        const short* wobase = wof + (size_t)h * 16 * 512;

        float tsum[4] = {0.f, 0.f, 0.f, 0.f};
        f32x4 o0 = z4, o1 = z4;

#pragma unroll
        for (int qt = 0; qt < 4; ++qt) {
            f32x4 sc[4];
#pragma unroll
            for (int s4 = 0; s4 < 4; ++s4) {
                bf16x8 bk = *(const bf16x8*)&KV[(qt * 4 + s4) * 512 + lane * 8];
                sc[s4] = MFMA16(aqh[h], bk, sc[s4] = z4);
            }
#pragma unroll
            for (int s4 = 0; s4 < 4; ++s4)
#pragma unroll
                for (int r = 0; r < 4; ++r) {
                    sc[s4][r] = __expf(sc[s4][r]);
                    tsum[r] += sc[s4][r];
                }
#pragma unroll
            for (int s4 = 0; s4 < 4; ++s4)
#pragma unroll
                for (int r = 0; r < 4; ++r) {
                    int row = qd * 4 + r;
                    Pw[row * 64 + ((s4 * 2 + (l15 >> 3)) ^ (row & 7)) * 8 + (l15 & 7)] = f2bf(sc[s4][r]);
                }
#pragma unroll
            for (int ktl = 0; ktl < 2; ++ktl) {
                bf16x8 pa = *(const bf16x8*)&Pw[l15 * 64 + ((ktl * 4 + qd) ^ (l15 & 7)) * 8];
                int kt = qt * 2 + ktl;
                bf16x8 v0 = *(const bf16x8*)&KV[8192 + (kt * 2 + 0) * 512 + lane * 8];
                bf16x8 v1 = *(const bf16x8*)&KV[8192 + (kt * 2 + 1) * 512 + lane * 8];
                o0 = MFMA16(pa, v0, o0);
                o1 = MFMA16(pa, v1, o1);
            }
        }
        float il[4];
#pragma unroll
        for (int r = 0; r < 4; ++r) {
            float t = tsum[r];
            t += __shfl_xor(t, 1); t += __shfl_xor(t, 2);
            t += __shfl_xor(t, 4); t += __shfl_xor(t, 8);
            il[r] = 1.f / t;
        }
        // O -> Ot (aliased in Pw), key = row&3
#pragma unroll
        for (int r = 0; r < 4; ++r) {
            int row = qd * 4 + r;
            int key = row & 3;
            Ow[row * 32 + (((l15 >> 3) ^ key) & 3) * 8 + (l15 & 7)]       = f2bf(o0[r] * il[r]);
            Ow[row * 32 + (((2 + (l15 >> 3)) ^ key) & 3) * 8 + (l15 & 7)] = f2bf(o1[r] * il[r]);
        }

        // all waves done reading K/V of head h -> safe to overwrite
        __syncthreads();
        if (h < 7) {
            const size_t nb = (size_t)(b * NHD + h + 1) * 8192;
            stage_tile(kf + nb, KV, tid);          // overlaps oproj below
            stage_tile(vf + nb, KV + 8192, tid);
        }

        // oproj (WO stays per-wave global; Ow is wave-private Pb, untouched by staging)
        bf16x8 bo = *(const bf16x8*)&Ow[l15 * 32 + ((qd ^ (l15 & 3)) & 3) * 8];
#pragma unroll
        for (int mt = 0; mt < 16; ++mt) {
            bf16x8 ao = *(const bf16x8*)&wobase[mt * 512 + lane * 8];
            acc_co[mt] = MFMA16(ao, bo, acc_co[mt]);
        }
    }

    // ---------------- epilogue: rows = co, cols = n -> coalesced stores ----
#pragma unroll
    for (int mt = 0; mt < 16; ++mt)
#pragma unroll
        for (int r = 0; r < 4; ++r) {
            int co = mt * 16 + qd * 4 + r;
            out[(size_t)(b * C_ + co) * N_ + n0 + wv * 16 + l15] = acc_co[mt][r] + o_b[co];
        }
}

// ---------------------------------------------------------------------------
extern "C" void kernel_launch(void* const* d_in, const int* in_sizes, int n_in,
                              void* d_out, int out_size, void* d_ws, size_t ws_size,
                              hipStream_t stream) {
    (void)in_sizes; (void)n_in; (void)out_size; (void)ws_size;
    const float* fv   = (const float*)d_in[0];
    const float* text = (const float*)d_in[1];
    const float* q_w  = (const float*)d_in[2];
    const float* q_b  = (const float*)d_in[3];
    const float* k_w  = (const float*)d_in[4];
    const float* k_b  = (const float*)d_in[5];
    const float* v_w  = (const float*)d_in[6];
    const float* v_b  = (const float*)d_in[7];
    const float* o_w  = (const float*)d_in[8];
    const float* o_b  = (const float*)d_in[9];
    const float* m1_w = (const float*)d_in[10];
    const float* m1_b = (const float*)d_in[11];
    const float* m2_w = (const float*)d_in[12];
    const float* m2_b = (const float*)d_in[13];
    float* out = (float*)d_out;

    short* wsS  = (short*)d_ws;
    short* kf   = wsS;                      // 131072 shorts
    short* vf   = wsS + 131072;             // 131072
    short* wqf  = wsS + 262144;             // 65536
    short* wof  = wsS + 327680;             // 65536
    short* fvtf = wsS + 393216;             // 16777216 (33.5 MB)

    hipLaunchKernelGGL(prep_fvtf, dim3(256, 4, 2), dim3(256), 0, stream, fv, fvtf);
    hipLaunchKernelGGL(prep_wf, dim3(64), dim3(256), 0, stream, q_w, o_w, wqf, wof);
    hipLaunchKernelGGL(text_stage, dim3(512), dim3(256), 0, stream,
                       text, k_w, k_b, v_w, v_b, m1_w, m1_b, m2_w, m2_b, kf, vf);
    hipLaunchKernelGGL(fused_visual, dim3(512, 2), dim3(256), 0, stream,
                       fvtf, wqf, q_b, kf, vf, wof, o_b, out);
}

// Round 2
// 343.468 us; speedup vs baseline: 1.1521x; 1.1521x over previous
//
#include <hip/hip_runtime.h>
#include <hip/hip_bf16.h>

#define NHD 8
#define HD  32
#define C_  256
#define TD_ 512
#define S_  256
#define N_  32768   // D*H*W
#define B_  2

typedef short bf16x8 __attribute__((ext_vector_type(8)));
typedef short bf16x4 __attribute__((ext_vector_type(4)));
typedef float f32x4  __attribute__((ext_vector_type(4)));

#define MFMA16(a,b,c) __builtin_amdgcn_mfma_f32_16x16x32_bf16(a,b,c,0,0,0)

__device__ __forceinline__ short f2bf(float f){
    __hip_bfloat16 h = __float2bfloat16(f);
    return *reinterpret_cast<short*>(&h);
}

// ---------------------------------------------------------------------------
// prep_fvtf (verified R6): fv f32 [b][c][n] -> fragment-ordered bf16
//   fvtf[b][ntile][cc][lane][8] = fv[b][cc*32+(lane>>4)*8+j][ntile*16+(lane&15)]
// ---------------------------------------------------------------------------
__global__ __launch_bounds__(256) void prep_fvtf(
    const float* __restrict__ fv, short* __restrict__ fvtf)
{
    __shared__ short Ts[64 * 128];   // 16 KB
    const int t = threadIdx.x;
    const int n0 = blockIdx.x * 128, c0 = blockIdx.y * 64, b = blockIdx.z;

#pragma unroll
    for (int i = 0; i < 8; ++i) {
        int c_loc = (t >> 5) + 8 * i;            // 0..63
        int u = t & 31;                           // n-unit (4 floats)
        float4 v = *(const float4*)&fv[(size_t)(b * C_ + c0 + c_loc) * N_ + n0 + u * 4];
        int up = u ^ (c_loc & 31);
        bf16x4 s4 = { f2bf(v.x), f2bf(v.y), f2bf(v.z), f2bf(v.w) };
        *(bf16x4*)&Ts[c_loc * 128 + up * 4] = s4;
    }
    __syncthreads();
#pragma unroll
    for (int p = 0; p < 4; ++p) {
        int idx = p * 256 + t;                    // 0..1023
        int lane = idx & 63, ccl = (idx >> 6) & 1, ntl = idx >> 7;
        bf16x8 r;
#pragma unroll
        for (int k = 0; k < 8; ++k) {
            int c = ccl * 32 + (lane >> 4) * 8 + k;
            int n = ntl * 16 + (lane & 15);
            r[k] = Ts[c * 128 + ((n >> 2) ^ (c & 31)) * 4 + (n & 3)];
        }
        size_t chunk = ((size_t)b * 2048 + (n0 >> 4) + ntl) * 8 + (c0 >> 5) + ccl;
        *(bf16x8*)&fvtf[chunk * 512 + lane * 8] = r;
    }
}

// ---------------------------------------------------------------------------
// prep_wf (verified R6): q_w/o_w fp32 [c][co] -> fragment-ordered bf16
// ---------------------------------------------------------------------------
__global__ __launch_bounds__(256) void prep_wf(
    const float* __restrict__ qw, const float* __restrict__ ow,
    short* __restrict__ wqf, short* __restrict__ wof)
{
    int gid = blockIdx.x * 256 + threadIdx.x;   // 64 blocks -> 16384
    int m = gid >> 13;
    int rest = gid & 8191;
    const float* src = m ? ow : qw;
    short* dst = m ? wof : wqf;
    int lane = rest & 63;
    int l15 = lane & 15, qd = lane >> 4;
    int cbase, co;
    if (m == 0) { int nt = rest >> 9, cc = (rest >> 6) & 7; cbase = cc * 32 + qd * 8; co = nt * 16 + l15; }
    else        { int hm = rest >> 6; cbase = (hm >> 4) * 32 + qd * 8; co = (hm & 15) * 16 + l15; }
    bf16x8 r;
#pragma unroll
    for (int j = 0; j < 8; ++j) r[j] = f2bf(src[(size_t)(cbase + j) * 256 + co]);
    *(bf16x8*)&dst[(size_t)rest * 8] = r;
}

// ---------------------------------------------------------------------------
// text stage (math verified R6; 1 token/block, 512 blocks).
// Outputs fragment-ordered kf/vf, indexing identical to R6.
// ---------------------------------------------------------------------------
__global__ __launch_bounds__(256) void text_stage(
    const float* __restrict__ text,
    const float* __restrict__ k_w, const float* __restrict__ k_b,
    const float* __restrict__ v_w, const float* __restrict__ v_b,
    const float* __restrict__ m1_w, const float* __restrict__ m1_b,
    const float* __restrict__ m2_w, const float* __restrict__ m2_b,
    short* __restrict__ kf, short* __restrict__ vf)
{
    __shared__ float t_s[TD_];
    __shared__ float h_s[C_];
    __shared__ float k_s[C_];
    const int tid = threadIdx.x;
    const int token = blockIdx.x;      // 0..511

    float2 tt = *(const float2*)&text[(size_t)token * TD_ + tid * 2];
    t_s[tid * 2] = tt.x; t_s[tid * 2 + 1] = tt.y;
    __syncthreads();

    float kv = k_b[tid], vv = v_b[tid], hv = m1_b[tid];
#pragma unroll 4
    for (int j = 0; j < TD_; ++j) {
        float tj = t_s[j];
        kv += tj * k_w[j * C_ + tid];
        vv += tj * v_w[j * C_ + tid];
        hv += tj * m1_w[j * C_ + tid];
    }
    float hg = 0.5f * hv * (1.0f + erff(hv * 0.70710678118654752f));
    h_s[tid] = hg;
    k_s[tid] = kv;
    __syncthreads();

    float ph = m2_b[tid];
#pragma unroll 4
    for (int j = 0; j < C_; ++j)
        ph += h_s[j] * m2_w[j * C_ + tid];

    const int t = tid & (HD - 1);
    const int nh = tid >> 5;
    const int b = token >> 8, s = token & (S_ - 1);
    const int bh = b * NHD + nh;
    float partner = (t < 16) ? -k_s[tid + 16] : k_s[tid - 16];
    float kr = kv * cosf(ph) + partner * sinf(ph);
    kf[(((size_t)bh * 16 + (s >> 4)) * 64 + (t >> 3) * 16 + (s & 15)) * 8 + (t & 7)] = f2bf(kr);
    vf[((((size_t)bh * 8 + (s >> 5)) * 2 + (t >> 4)) * 64 + ((s >> 3) & 3) * 16 + (t & 15)) * 8 + (s & 7)] = f2bf(vv);
}

// 3D rope freq (verified R3/R4/R6)
__device__ __forceinline__ float freq3d(int t, int n){
    int d = n >> 10, h = (n >> 5) & 31, w = n & 31;
    float pos, ex;
    if (t < 10)      { pos = (float)d; ex = (float)(2 * (t % 5)) * 0.1f; }
    else if (t < 20) { pos = (float)h; ex = (float)(2 * ((t - 10) % 5)) * 0.1f; }
    else             { pos = (float)w; ex = (float)(2 * ((t - 20) % 6)) * (1.0f / 12.0f); }
    return pos * expf(-ex * 9.210340371976184f);
}

// ---------------------------------------------------------------------------
// async global->LDS staging (16B/lane, linear; verified R1 — passed).
// LDS dest is wave-uniform base + lane*16 (HW semantics); global src per-lane.
// ---------------------------------------------------------------------------
typedef __attribute__((address_space(3))) unsigned int lds_u32;
typedef const __attribute__((address_space(1))) unsigned int glb_u32;

__device__ __forceinline__ void async_cp16(const short* g, short* l){
    __builtin_amdgcn_global_load_lds(
        (glb_u32*)(unsigned long long)g,
        (lds_u32*)(unsigned int)(unsigned long long)l,
        16, 0, 0);
}

// stage one 16 KB verbatim tile (8192 shorts): 4 rounds x 256 thr x 16B
__device__ __forceinline__ void stage_tile(const short* __restrict__ g, short* l, int tid){
    const int wvb = tid & 192;            // (tid>>6)<<6 : wave-uniform
#pragma unroll
    for (int r = 0; r < 4; ++r)
        async_cp16(g + (r * 256 + tid) * 8, l + (r * 256 + wvb) * 8);
}

// ---------------------------------------------------------------------------
// FUSED: qproj + RoPE + attention + oproj.
// R2 structure: (256,4) restored — 4 blocks/CU, 1024 blocks = zero tail.
// 2-slot x 16KB double-buffered staging ring (m97 2-phase pipeline) for the
// block-shareable streams: wq tiles 0..7, then per head {K(h), WO(h)}.
// Every staged tile is a verbatim-contiguous 16KB copy; consuming fragment
// offsets inside a tile are identical to the R0 global offsets -> bit-identical
// math. V stays global (3rd live slot would cost half the occupancy).
// LDS = Stg 32KB + Pb 8KB = 40KB exactly.
// Prologue reuses Stg as wave-private Q-transpose scratch (8KB/wave).
// ---------------------------------------------------------------------------
__global__ __launch_bounds__(256, 4) void fused_visual(
    const short* __restrict__ fvtf, const short* __restrict__ wqf,
    const float* __restrict__ q_b, const short* __restrict__ kf,
    const short* __restrict__ vf, const short* __restrict__ wof,
    const float* __restrict__ o_b, float* __restrict__ out)
{
    __shared__ __align__(16) short Stg[16384];      // 2 slots x 8192 shorts (16KB each)
    __shared__ __align__(16) short Pb[4 * 16 * 64]; // 8 KB (P; Ot aliases)
    const int tid = threadIdx.x;
    const int lane = tid & 63;
    const int l15 = tid & 15, qd = (tid >> 4) & 3, wv = tid >> 6;
    const int n0 = blockIdx.x * 64;
    const int b = blockIdx.y;
    const f32x4 z4 = {0.f, 0.f, 0.f, 0.f};
    const float scale = 0.17677669529663687f;  // 32^-0.5, folded into Q

    short* slot0 = Stg;
    short* slot1 = Stg + 8192;

    // ---------------- qproj (staged-ring wq) ----------------
    f32x4 acc[16];
#pragma unroll
    for (int i = 0; i < 16; ++i) acc[i] = z4;

    // A-frags for all 8 cc in registers (8 x b128 global, 32 VGPRs)
    bf16x8 af[8];
    {
        const short* abase = fvtf + ((size_t)b * 2048 + (n0 >> 4) + wv) * 8 * 512 + lane * 8;
#pragma unroll
        for (int cc = 0; cc < 8; ++cc) af[cc] = *(const bf16x8*)(abase + cc * 512);
    }
    stage_tile(wqf, slot0, tid);     // wq tile 0

#pragma unroll
    for (int ntp = 0; ntp < 8; ++ntp) {
        __syncthreads();             // wq tile ntp landed
        if (ntp < 7) stage_tile(wqf + (ntp + 1) * 8192, (ntp & 1) ? slot0 : slot1, tid);
        const short* sb = (ntp & 1) ? slot1 : slot0;
#pragma unroll
        for (int cc = 0; cc < 8; ++cc)
#pragma unroll
            for (int ntl = 0; ntl < 2; ++ntl) {
                bf16x8 bq = *(const bf16x8*)&sb[((ntl * 8 + cc) * 64 + lane) * 8];
                acc[ntp * 2 + ntl] = MFMA16(af[cc], bq, acc[ntp * 2 + ntl]);
            }
    }
    __syncthreads();   // all waves done with last wq tile; Stg reusable as scratch

    // ---------------- RoPE -> wave-private scratch, aqh[] to regs ----------
    short* Qsc = Stg + wv * 4096;    // 8KB per wave (16 rows x 256 shorts)
#pragma unroll
    for (int r = 0; r < 4; ++r) {
        int lr = qd * 4 + r;                  // local row
        int n = n0 + wv * 16 + lr;
        int key = lr & 7;
        float f1 = freq3d(l15, n), f2 = freq3d(l15 + 16, n);
        float c1 = cosf(f1), s1 = sinf(f1), c2 = cosf(f2), s2 = sinf(f2);
#pragma unroll
        for (int hh = 0; hh < 8; ++hh) {
            float x1 = acc[2 * hh][r]     + q_b[hh * 32 + l15];
            float x2 = acc[2 * hh + 1][r] + q_b[hh * 32 + 16 + l15];
            int cb1 = (hh * 4 + (l15 >> 3)) ^ key;
            int cb2 = (hh * 4 + 2 + (l15 >> 3)) ^ key;
            Qsc[lr * 256 + cb1 * 8 + (l15 & 7)] = f2bf((x1 * c1 - x2 * s1) * scale);
            Qsc[lr * 256 + cb2 * 8 + (l15 & 7)] = f2bf((x2 * c2 + x1 * s2) * scale);
        }
    }
    // per-wave in-order DS: own writes visible to own reads without barrier
    bf16x8 aqh[8];
#pragma unroll
    for (int h = 0; h < 8; ++h)
        aqh[h] = *(const bf16x8*)&Qsc[l15 * 256 + ((h * 4 + qd) ^ (l15 & 7)) * 8];

    __syncthreads();   // all waves done with scratch -> slot0 free for K(0)
    stage_tile(kf + (size_t)(b * NHD) * 8192, slot0, tid);

    // ---------------- attention + accumulated oproj ----------------
    f32x4 acc_co[16];
#pragma unroll
    for (int i = 0; i < 16; ++i) acc_co[i] = z4;
    short* Pw = Pb + wv * 16 * 64;
    short* Ow = Pw;   // alias (per-wave in-order DS makes this safe)

#pragma unroll
    for (int h = 0; h < 8; ++h) {
        const int bh = b * NHD + h;
        __syncthreads();                                   // K(h) landed
        stage_tile(wof + (size_t)h * 8192, slot1, tid);    // WO(h): consumed after mid barrier

        const short* vbase = vf + (size_t)bh * 8192;

        float tsum[4] = {0.f, 0.f, 0.f, 0.f};
        f32x4 o0 = z4, o1 = z4;

#pragma unroll
        for (int qt = 0; qt < 4; ++qt) {
            f32x4 sc[4];
#pragma unroll
            for (int s4 = 0; s4 < 4; ++s4) {
                bf16x8 bk = *(const bf16x8*)&slot0[(qt * 4 + s4) * 512 + lane * 8];
                sc[s4] = MFMA16(aqh[h], bk, z4);
            }
#pragma unroll
            for (int s4 = 0; s4 < 4; ++s4)
#pragma unroll
                for (int r = 0; r < 4; ++r) {
                    sc[s4][r] = __expf(sc[s4][r]);
                    tsum[r] += sc[s4][r];
                }
#pragma unroll
            for (int s4 = 0; s4 < 4; ++s4)
#pragma unroll
                for (int r = 0; r < 4; ++r) {
                    int row = qd * 4 + r;
                    Pw[row * 64 + ((s4 * 2 + (l15 >> 3)) ^ (row & 7)) * 8 + (l15 & 7)] = f2bf(sc[s4][r]);
                }
#pragma unroll
            for (int ktl = 0; ktl < 2; ++ktl) {
                bf16x8 pa = *(const bf16x8*)&Pw[l15 * 64 + ((ktl * 4 + qd) ^ (l15 & 7)) * 8];
                int kt = qt * 2 + ktl;
                bf16x8 v0 = *(const bf16x8*)&vbase[(kt * 2 + 0) * 512 + lane * 8];
                bf16x8 v1 = *(const bf16x8*)&vbase[(kt * 2 + 1) * 512 + lane * 8];
                o0 = MFMA16(pa, v0, o0);
                o1 = MFMA16(pa, v1, o1);
            }
        }
        float il[4];
#pragma unroll
        for (int r = 0; r < 4; ++r) {
            float t = tsum[r];
            t += __shfl_xor(t, 1); t += __shfl_xor(t, 2);
            t += __shfl_xor(t, 4); t += __shfl_xor(t, 8);
            il[r] = 1.f / t;
        }
        // O -> Ot (aliased in Pw), key = row&3
#pragma unroll
        for (int r = 0; r < 4; ++r) {
            int row = qd * 4 + r;
            int key = row & 3;
            Ow[row * 32 + (((l15 >> 3) ^ key) & 3) * 8 + (l15 & 7)]       = f2bf(o0[r] * il[r]);
            Ow[row * 32 + (((2 + (l15 >> 3)) ^ key) & 3) * 8 + (l15 & 7)] = f2bf(o1[r] * il[r]);
        }

        __syncthreads();   // WO(h) landed; all waves done reading K(h) -> slot0 free
        if (h < 7)
            stage_tile(kf + (size_t)(bh + 1) * 8192, slot0, tid);  // covered by oproj

        // oproj from slot1 (LDS); Ow is wave-private Pb, untouched by staging
        bf16x8 bo = *(const bf16x8*)&Ow[l15 * 32 + ((qd ^ (l15 & 3)) & 3) * 8];
#pragma unroll
        for (int mt = 0; mt < 16; ++mt) {
            bf16x8 ao = *(const bf16x8*)&slot1[mt * 512 + lane * 8];
            acc_co[mt] = MFMA16(ao, bo, acc_co[mt]);
        }
    }

    // ---------------- epilogue: rows = co, cols = n -> coalesced stores ----
#pragma unroll
    for (int mt = 0; mt < 16; ++mt)
#pragma unroll
        for (int r = 0; r < 4; ++r) {
            int co = mt * 16 + qd * 4 + r;
            out[(size_t)(b * C_ + co) * N_ + n0 + wv * 16 + l15] = acc_co[mt][r] + o_b[co];
        }
}

// ---------------------------------------------------------------------------
extern "C" void kernel_launch(void* const* d_in, const int* in_sizes, int n_in,
                              void* d_out, int out_size, void* d_ws, size_t ws_size,
                              hipStream_t stream) {
    (void)in_sizes; (void)n_in; (void)out_size; (void)ws_size;
    const float* fv   = (const float*)d_in[0];
    const float* text = (const float*)d_in[1];
    const float* q_w  = (const float*)d_in[2];
    const float* q_b  = (const float*)d_in[3];
    const float* k_w  = (const float*)d_in[4];
    const float* k_b  = (const float*)d_in[5];
    const float* v_w  = (const float*)d_in[6];
    const float* v_b  = (const float*)d_in[7];
    const float* o_w  = (const float*)d_in[8];
    const float* o_b  = (const float*)d_in[9];
    const float* m1_w = (const float*)d_in[10];
    const float* m1_b = (const float*)d_in[11];
    const float* m2_w = (const float*)d_in[12];
    const float* m2_b = (const float*)d_in[13];
    float* out = (float*)d_out;

    short* wsS  = (short*)d_ws;
    short* kf   = wsS;                      // 131072 shorts
    short* vf   = wsS + 131072;             // 131072
    short* wqf  = wsS + 262144;             // 65536
    short* wof  = wsS + 327680;             // 65536
    short* fvtf = wsS + 393216;             // 16777216 (33.5 MB)

    hipLaunchKernelGGL(prep_fvtf, dim3(256, 4, 2), dim3(256), 0, stream, fv, fvtf);
    hipLaunchKernelGGL(prep_wf, dim3(64), dim3(256), 0, stream, q_w, o_w, wqf, wof);
    hipLaunchKernelGGL(text_stage, dim3(512), dim3(256), 0, stream,
                       text, k_w, k_b, v_w, v_b, m1_w, m1_b, m2_w, m2_b, kf, vf);
    hipLaunchKernelGGL(fused_visual, dim3(512, 2), dim3(256), 0, stream,
                       fvtf, wqf, q_b, kf, vf, wof, o_b, out);
}

// Round 3
// 270.039 us; speedup vs baseline: 1.4654x; 1.2719x over previous
//
#include <hip/hip_runtime.h>
#include <hip/hip_bf16.h>

#define NHD 8
#define HD  32
#define C_  256
#define TD_ 512
#define S_  256
#define N_  32768   // D*H*W
#define B_  2

typedef short bf16x8 __attribute__((ext_vector_type(8)));
typedef short bf16x4 __attribute__((ext_vector_type(4)));
typedef float f32x4  __attribute__((ext_vector_type(4)));

#define MFMA16(a,b,c) __builtin_amdgcn_mfma_f32_16x16x32_bf16(a,b,c,0,0,0)

__device__ __forceinline__ short f2bf(float f){
    __hip_bfloat16 h = __float2bfloat16(f);
    return *reinterpret_cast<short*>(&h);
}

// ---------------------------------------------------------------------------
// async global->LDS staging (16B/lane, linear dest; verified R1/R2).
// LDS dest is wave-uniform base + lane*16 (HW semantics); global src per-lane.
// ---------------------------------------------------------------------------
typedef __attribute__((address_space(3))) unsigned int lds_u32;
typedef const __attribute__((address_space(1))) unsigned int glb_u32;

__device__ __forceinline__ void async_cp16(const void* g, void* l){
    __builtin_amdgcn_global_load_lds(
        (glb_u32*)(unsigned long long)g,
        (lds_u32*)(unsigned int)(unsigned long long)l,
        16, 0, 0);
}

// stage one 16 KB verbatim tile (8192 shorts): 4 rounds x 256 thr x 16B
__device__ __forceinline__ void stage_tile(const short* __restrict__ g, short* l, int tid){
    const int wvb = tid & 192;            // (tid>>6)<<6 : wave-uniform
#pragma unroll
    for (int r = 0; r < 4; ++r)
        async_cp16(g + (r * 256 + tid) * 8, l + (r * 256 + wvb) * 8);
}

// ---------------------------------------------------------------------------
// text_stage v2: register-double-buffered MLP pipeline (chunk-16, ~48 loads
// in flight vs unroll-4's ~12 — was latency-bound at 2 blocks/CU).
// Summation order per j unchanged -> bit-identical math to R2 (verified).
// prep_wf folded in as blocks 512..575 (body verbatim from verified R6 prep_wf).
// ---------------------------------------------------------------------------
#define TS_LD(Ka, Va, Ma, Ta, j0) \
    _Pragma("unroll") for (int i = 0; i < 16; ++i) { \
        Ka[i] = kp[(j0 + i) * C_]; Va[i] = vp[(j0 + i) * C_]; \
        Ma[i] = mp[(j0 + i) * C_]; Ta[i] = t_s[(j0) + i]; }
#define TS_FM(Ka, Va, Ma, Ta) \
    _Pragma("unroll") for (int i = 0; i < 16; ++i) { \
        kv += Ta[i] * Ka[i]; vv += Ta[i] * Va[i]; hv += Ta[i] * Ma[i]; }
#define M2_LD(Ha, Ga, j0) \
    _Pragma("unroll") for (int i = 0; i < 16; ++i) { \
        Ha[i] = h_s[(j0) + i]; Ga[i] = m2p[(j0 + i) * C_]; }
#define M2_FM(Ha, Ga) \
    _Pragma("unroll") for (int i = 0; i < 16; ++i) { ph += Ha[i] * Ga[i]; }

__global__ __launch_bounds__(256, 2) void text_stage(
    const float* __restrict__ text,
    const float* __restrict__ k_w, const float* __restrict__ k_b,
    const float* __restrict__ v_w, const float* __restrict__ v_b,
    const float* __restrict__ m1_w, const float* __restrict__ m1_b,
    const float* __restrict__ m2_w, const float* __restrict__ m2_b,
    const float* __restrict__ qw, const float* __restrict__ ow,
    short* __restrict__ kf, short* __restrict__ vf,
    short* __restrict__ wqf, short* __restrict__ wof)
{
    const int tid = threadIdx.x;

    if (blockIdx.x >= 512) {
        // ---- prep_wf fold (body verbatim from verified prep_wf) ----
        int gid = (blockIdx.x - 512) * 256 + tid;   // 0..16383
        int m = gid >> 13;
        int rest = gid & 8191;
        const float* src = m ? ow : qw;
        short* dst = m ? wof : wqf;
        int lane = rest & 63;
        int l15 = lane & 15, qd = lane >> 4;
        int cbase, co;
        if (m == 0) { int nt = rest >> 9, cc = (rest >> 6) & 7; cbase = cc * 32 + qd * 8; co = nt * 16 + l15; }
        else        { int hm = rest >> 6; cbase = (hm >> 4) * 32 + qd * 8; co = (hm & 15) * 16 + l15; }
        bf16x8 r;
#pragma unroll
        for (int j = 0; j < 8; ++j) r[j] = f2bf(src[(size_t)(cbase + j) * 256 + co]);
        *(bf16x8*)&dst[(size_t)rest * 8] = r;
        return;
    }

    __shared__ float t_s[TD_];
    __shared__ float h_s[C_];
    __shared__ float k_s[C_];
    const int token = blockIdx.x;      // 0..511

    float2 tt = *(const float2*)&text[(size_t)token * TD_ + tid * 2];
    t_s[tid * 2] = tt.x; t_s[tid * 2 + 1] = tt.y;
    __syncthreads();

    float kv = k_b[tid], vv = v_b[tid], hv = m1_b[tid];
    const float* kp = k_w + tid;
    const float* vp = v_w + tid;
    const float* mp = m1_w + tid;

    {
        float Ka[16], Va[16], Ma[16], Ta[16];
        float Kb[16], Vb[16], Mb[16], Tb[16];
        TS_LD(Ka, Va, Ma, Ta, 0);
#pragma unroll 1
        for (int jb = 0; jb < TD_; jb += 32) {
            TS_LD(Kb, Vb, Mb, Tb, jb + 16);
            TS_FM(Ka, Va, Ma, Ta);
            if (jb + 32 < TD_) { TS_LD(Ka, Va, Ma, Ta, jb + 32); }
            TS_FM(Kb, Vb, Mb, Tb);
        }
    }

    float hg = 0.5f * hv * (1.0f + erff(hv * 0.70710678118654752f));
    h_s[tid] = hg;
    k_s[tid] = kv;
    __syncthreads();

    float ph = m2_b[tid];
    const float* m2p = m2_w + tid;
    {
        float Ha[16], Ga[16], Hb[16], Gb[16];
        M2_LD(Ha, Ga, 0);
#pragma unroll 1
        for (int jb = 0; jb < C_; jb += 32) {
            M2_LD(Hb, Gb, jb + 16);
            M2_FM(Ha, Ga);
            if (jb + 32 < C_) { M2_LD(Ha, Ga, jb + 32); }
            M2_FM(Hb, Gb);
        }
    }

    const int t = tid & (HD - 1);
    const int nh = tid >> 5;
    const int b = token >> 8, s = token & (S_ - 1);
    const int bh = b * NHD + nh;
    float partner = (t < 16) ? -k_s[tid + 16] : k_s[tid - 16];
    float kr = kv * cosf(ph) + partner * sinf(ph);
    kf[(((size_t)bh * 16 + (s >> 4)) * 64 + (t >> 3) * 16 + (s & 15)) * 8 + (t & 7)] = f2bf(kr);
    vf[((((size_t)bh * 8 + (s >> 5)) * 2 + (t >> 4)) * 64 + ((s >> 3) & 3) * 16 + (t & 15)) * 8 + (s & 7)] = f2bf(vv);
}

// 3D rope freq (verified R3/R4/R6)
__device__ __forceinline__ float freq3d(int t, int n){
    int d = n >> 10, h = (n >> 5) & 31, w = n & 31;
    float pos, ex;
    if (t < 10)      { pos = (float)d; ex = (float)(2 * (t % 5)) * 0.1f; }
    else if (t < 20) { pos = (float)h; ex = (float)(2 * ((t - 10) % 5)) * 0.1f; }
    else             { pos = (float)w; ex = (float)(2 * ((t - 20) % 6)) * (1.0f / 12.0f); }
    return pos * expf(-ex * 9.210340371976184f);
}

// ---------------------------------------------------------------------------
// FUSED: A-transpose (ex prep_fvtf) + qproj + RoPE + attention + oproj.
// R3: fv is read DIRECTLY (prep_fvtf deleted). Prologue stages two 32KB
// f32 c-halves into Stg via global_load_lds with PRE-SWIZZLED global source
// (LDS linear, u' = w ^ (c_loc&15)); each wave gathers its af[8] fragments
// with scalar f32 LDS reads + f2bf. Gather math identical to verified
// prep_fvtf semantics: af[cc][j] = bf16(fv[b][cc*32+qd*8+j][n0+wv*16+l15]).
// Everything after the prologue is the verified R2 structure unchanged.
// ---------------------------------------------------------------------------
__global__ __launch_bounds__(256, 4) void fused_visual(
    const float* __restrict__ fv, const short* __restrict__ wqf,
    const float* __restrict__ q_b, const short* __restrict__ kf,
    const short* __restrict__ vf, const short* __restrict__ wof,
    const float* __restrict__ o_b, float* __restrict__ out)
{
    __shared__ __align__(16) short Stg[16384];      // 2 slots x 8192 shorts (16KB each)
    __shared__ __align__(16) short Pb[4 * 16 * 64]; // 8 KB (P; Ot aliases)
    const int tid = threadIdx.x;
    const int lane = tid & 63;
    const int l15 = tid & 15, qd = (tid >> 4) & 3, wv = tid >> 6;
    const int n0 = blockIdx.x * 64;
    const int b = blockIdx.y;
    const f32x4 z4 = {0.f, 0.f, 0.f, 0.f};
    const float scale = 0.17677669529663687f;  // 32^-0.5, folded into Q

    short* slot0 = Stg;
    short* slot1 = Stg + 8192;

    // ---------------- A-operand: fv -> af[8] (2 c-halves x 32KB) ----------
    bf16x8 af[8];
    const float* Tsf = (const float*)Stg;
#pragma unroll
    for (int ch = 0; ch < 2; ++ch) {
        // stage: 128 c-rows x 64 n f32; LDS linear, source pre-swizzled
#pragma unroll
        for (int r = 0; r < 8; ++r) {
            int slot = r * 256 + tid;                 // 0..2047
            int c_loc = slot >> 4;
            int u = (slot & 15) ^ (c_loc & 15);       // pre-swizzled n-chunk
            async_cp16(fv + (size_t)(b * C_ + ch * 128 + c_loc) * N_ + n0 + u * 4,
                       Stg + (r * 256 + (tid & 192)) * 8);
        }
        __syncthreads();   // staged half landed (vmcnt(0) before barrier)
#pragma unroll
        for (int cc2 = 0; cc2 < 4; ++cc2) {
            bf16x8 a;
#pragma unroll
            for (int j = 0; j < 8; ++j) {
                int c_loc = cc2 * 32 + qd * 8 + j;    // 0..127
                int u = (wv * 4 + (l15 >> 2)) ^ (c_loc & 15);
                float x = Tsf[c_loc * 64 + u * 4 + (l15 & 3)];
                a[j] = f2bf(x);
            }
            af[ch * 4 + cc2] = a;
        }
        __syncthreads();   // all gathers done before Stg is overwritten
    }

    // ---------------- qproj (staged-ring wq; verified R2) ----------------
    f32x4 acc[16];
#pragma unroll
    for (int i = 0; i < 16; ++i) acc[i] = z4;

    stage_tile(wqf, slot0, tid);     // wq tile 0

#pragma unroll
    for (int ntp = 0; ntp < 8; ++ntp) {
        __syncthreads();             // wq tile ntp landed
        if (ntp < 7) stage_tile(wqf + (ntp + 1) * 8192, (ntp & 1) ? slot0 : slot1, tid);
        const short* sb = (ntp & 1) ? slot1 : slot0;
#pragma unroll
        for (int cc = 0; cc < 8; ++cc)
#pragma unroll
            for (int ntl = 0; ntl < 2; ++ntl) {
                bf16x8 bq = *(const bf16x8*)&sb[((ntl * 8 + cc) * 64 + lane) * 8];
                acc[ntp * 2 + ntl] = MFMA16(af[cc], bq, acc[ntp * 2 + ntl]);
            }
    }
    __syncthreads();   // all waves done with last wq tile; Stg reusable as scratch

    // ---------------- RoPE -> wave-private scratch, aqh[] to regs ----------
    short* Qsc = Stg + wv * 4096;    // 8KB per wave (16 rows x 256 shorts)
#pragma unroll
    for (int r = 0; r < 4; ++r) {
        int lr = qd * 4 + r;                  // local row
        int n = n0 + wv * 16 + lr;
        int key = lr & 7;
        float f1 = freq3d(l15, n), f2 = freq3d(l15 + 16, n);
        float c1 = cosf(f1), s1 = sinf(f1), c2 = cosf(f2), s2 = sinf(f2);
#pragma unroll
        for (int hh = 0; hh < 8; ++hh) {
            float x1 = acc[2 * hh][r]     + q_b[hh * 32 + l15];
            float x2 = acc[2 * hh + 1][r] + q_b[hh * 32 + 16 + l15];
            int cb1 = (hh * 4 + (l15 >> 3)) ^ key;
            int cb2 = (hh * 4 + 2 + (l15 >> 3)) ^ key;
            Qsc[lr * 256 + cb1 * 8 + (l15 & 7)] = f2bf((x1 * c1 - x2 * s1) * scale);
            Qsc[lr * 256 + cb2 * 8 + (l15 & 7)] = f2bf((x2 * c2 + x1 * s2) * scale);
        }
    }
    // per-wave in-order DS: own writes visible to own reads without barrier
    bf16x8 aqh[8];
#pragma unroll
    for (int h = 0; h < 8; ++h)
        aqh[h] = *(const bf16x8*)&Qsc[l15 * 256 + ((h * 4 + qd) ^ (l15 & 7)) * 8];

    __syncthreads();   // all waves done with scratch -> slot0 free for K(0)
    stage_tile(kf + (size_t)(b * NHD) * 8192, slot0, tid);

    // ---------------- attention + accumulated oproj ----------------
    f32x4 acc_co[16];
#pragma unroll
    for (int i = 0; i < 16; ++i) acc_co[i] = z4;
    short* Pw = Pb + wv * 16 * 64;
    short* Ow = Pw;   // alias (per-wave in-order DS makes this safe)

#pragma unroll
    for (int h = 0; h < 8; ++h) {
        const int bh = b * NHD + h;
        __syncthreads();                                   // K(h) landed
        stage_tile(wof + (size_t)h * 8192, slot1, tid);    // WO(h): consumed after mid barrier

        const short* vbase = vf + (size_t)bh * 8192;

        float tsum[4] = {0.f, 0.f, 0.f, 0.f};
        f32x4 o0 = z4, o1 = z4;

#pragma unroll
        for (int qt = 0; qt < 4; ++qt) {
            f32x4 sc[4];
#pragma unroll
            for (int s4 = 0; s4 < 4; ++s4) {
                bf16x8 bk = *(const bf16x8*)&slot0[(qt * 4 + s4) * 512 + lane * 8];
                sc[s4] = MFMA16(aqh[h], bk, z4);
            }
#pragma unroll
            for (int s4 = 0; s4 < 4; ++s4)
#pragma unroll
                for (int r = 0; r < 4; ++r) {
                    sc[s4][r] = __expf(sc[s4][r]);
                    tsum[r] += sc[s4][r];
                }
#pragma unroll
            for (int s4 = 0; s4 < 4; ++s4)
#pragma unroll
                for (int r = 0; r < 4; ++r) {
                    int row = qd * 4 + r;
                    Pw[row * 64 + ((s4 * 2 + (l15 >> 3)) ^ (row & 7)) * 8 + (l15 & 7)] = f2bf(sc[s4][r]);
                }
#pragma unroll
            for (int ktl = 0; ktl < 2; ++ktl) {
                bf16x8 pa = *(const bf16x8*)&Pw[l15 * 64 + ((ktl * 4 + qd) ^ (l15 & 7)) * 8];
                int kt = qt * 2 + ktl;
                bf16x8 v0 = *(const bf16x8*)&vbase[(kt * 2 + 0) * 512 + lane * 8];
                bf16x8 v1 = *(const bf16x8*)&vbase[(kt * 2 + 1) * 512 + lane * 8];
                o0 = MFMA16(pa, v0, o0);
                o1 = MFMA16(pa, v1, o1);
            }
        }
        float il[4];
#pragma unroll
        for (int r = 0; r < 4; ++r) {
            float t = tsum[r];
            t += __shfl_xor(t, 1); t += __shfl_xor(t, 2);
            t += __shfl_xor(t, 4); t += __shfl_xor(t, 8);
            il[r] = 1.f / t;
        }
        // O -> Ot (aliased in Pw), key = row&3
#pragma unroll
        for (int r = 0; r < 4; ++r) {
            int row = qd * 4 + r;
            int key = row & 3;
            Ow[row * 32 + (((l15 >> 3) ^ key) & 3) * 8 + (l15 & 7)]       = f2bf(o0[r] * il[r]);
            Ow[row * 32 + (((2 + (l15 >> 3)) ^ key) & 3) * 8 + (l15 & 7)] = f2bf(o1[r] * il[r]);
        }

        __syncthreads();   // WO(h) landed; all waves done reading K(h) -> slot0 free
        if (h < 7)
            stage_tile(kf + (size_t)(bh + 1) * 8192, slot0, tid);  // covered by oproj

        // oproj from slot1 (LDS); Ow is wave-private Pb, untouched by staging
        bf16x8 bo = *(const bf16x8*)&Ow[l15 * 32 + ((qd ^ (l15 & 3)) & 3) * 8];
#pragma unroll
        for (int mt = 0; mt < 16; ++mt) {
            bf16x8 ao = *(const bf16x8*)&slot1[mt * 512 + lane * 8];
            acc_co[mt] = MFMA16(ao, bo, acc_co[mt]);
        }
    }

    // ---------------- epilogue: rows = co, cols = n -> coalesced stores ----
#pragma unroll
    for (int mt = 0; mt < 16; ++mt)
#pragma unroll
        for (int r = 0; r < 4; ++r) {
            int co = mt * 16 + qd * 4 + r;
            out[(size_t)(b * C_ + co) * N_ + n0 + wv * 16 + l15] = acc_co[mt][r] + o_b[co];
        }
}

// ---------------------------------------------------------------------------
extern "C" void kernel_launch(void* const* d_in, const int* in_sizes, int n_in,
                              void* d_out, int out_size, void* d_ws, size_t ws_size,
                              hipStream_t stream) {
    (void)in_sizes; (void)n_in; (void)out_size; (void)ws_size;
    const float* fv   = (const float*)d_in[0];
    const float* text = (const float*)d_in[1];
    const float* q_w  = (const float*)d_in[2];
    const float* q_b  = (const float*)d_in[3];
    const float* k_w  = (const float*)d_in[4];
    const float* k_b  = (const float*)d_in[5];
    const float* v_w  = (const float*)d_in[6];
    const float* v_b  = (const float*)d_in[7];
    const float* o_w  = (const float*)d_in[8];
    const float* o_b  = (const float*)d_in[9];
    const float* m1_w = (const float*)d_in[10];
    const float* m1_b = (const float*)d_in[11];
    const float* m2_w = (const float*)d_in[12];
    const float* m2_b = (const float*)d_in[13];
    float* out = (float*)d_out;

    short* wsS  = (short*)d_ws;
    short* kf   = wsS;                      // 131072 shorts
    short* vf   = wsS + 131072;             // 131072
    short* wqf  = wsS + 262144;             // 65536
    short* wof  = wsS + 327680;             // 65536

    hipLaunchKernelGGL(text_stage, dim3(576), dim3(256), 0, stream,
                       text, k_w, k_b, v_w, v_b, m1_w, m1_b, m2_w, m2_b,
                       q_w, o_w, kf, vf, wqf, wof);
    hipLaunchKernelGGL(fused_visual, dim3(512, 2), dim3(256), 0, stream,
                       fv, wqf, q_b, kf, vf, wof, o_b, out);
}